// Round 5
// baseline (267.688 us; speedup 1.0000x reference)
//
#include <hip/hip_runtime.h>
#include <hip/hip_bf16.h>

#define E_MSGS 131072
#define N_NODES 8192
#define D_DIM 256
#define XA_STRIDE 280  // bf16 stride: (280*2/4)%32=12 -> A-frag b128 2-way (free)
#define SMAX 64        // per-node message cap (Poisson(16): max ~45)

typedef __bf16 bf16x8 __attribute__((ext_vector_type(8)));
typedef float f32x4 __attribute__((ext_vector_type(4)));

// raw workgroup barrier: drains LDS (lgkm) only — vmem prefetch stays in flight
#define BAR() asm volatile("s_waitcnt lgkmcnt(0)\n\ts_barrier" ::: "memory")

// ================= phase 1: counting sort + segment sort =================

__global__ void k_count(const int* __restrict__ index, int* __restrict__ counts) {
    int e = blockIdx.x * blockDim.x + threadIdx.x;
    if (e < E_MSGS) atomicAdd(&counts[index[e]], 1);
}

// single block, 1024 threads, 8 nodes/thread: scan counts->offsets + count-desc perm
__global__ void k_prep(const int* __restrict__ counts, int* __restrict__ offsets,
                       int* __restrict__ perm) {
    __shared__ int partial[1024];
    __shared__ int hist[256];
    __shared__ int hcur[256];
    int tid = threadIdx.x;
    if (tid < 256) hist[tid] = 0;
    __syncthreads();

    int base = tid * 8;
    int4 c0 = ((const int4*)counts)[tid * 2];
    int4 c1 = ((const int4*)counts)[tid * 2 + 1];
    int cs[8] = {c0.x, c0.y, c0.z, c0.w, c1.x, c1.y, c1.z, c1.w};
    int local[8];
    int sum = 0;
#pragma unroll
    for (int i = 0; i < 8; i++) {
        local[i] = sum;
        sum += cs[i];
        atomicAdd(&hist[min(cs[i], 255)], 1);
    }
    partial[tid] = sum;
    __syncthreads();
    for (int off = 1; off < 1024; off <<= 1) {
        int v = (tid >= off) ? partial[tid - off] : 0;
        __syncthreads();
        partial[tid] += v;
        __syncthreads();
    }
    int basesum = (tid > 0) ? partial[tid - 1] : 0;
#pragma unroll
    for (int i = 0; i < 8; i++) offsets[base + i] = basesum + local[i];
    if (tid == 1023) offsets[N_NODES] = partial[1023];
    __syncthreads();

    // descending-count starts: start[c] = sum_{c'>c} hist[c']
    if (tid < 256) partial[tid] = hist[255 - tid];
    __syncthreads();
    for (int off = 1; off < 256; off <<= 1) {
        int v = (tid < 256 && tid >= off) ? partial[tid - off] : 0;
        __syncthreads();
        if (tid < 256) partial[tid] += v;
        __syncthreads();
    }
    if (tid < 256) hcur[tid] = partial[255 - tid] - hist[tid];
    __syncthreads();
#pragma unroll
    for (int i = 0; i < 8; i++) {
        int c = min(cs[i], 255);
        int pos = atomicAdd(&hcur[c], 1);
        perm[pos] = base + i;
    }
}

__global__ void k_scatter(const int* __restrict__ index, const int* __restrict__ offsets,
                          int* __restrict__ cursors, int* __restrict__ bucket) {
    int e = blockIdx.x * blockDim.x + threadIdx.x;
    if (e < E_MSGS) {
        int n = index[e];
        int p = offsets[n] + atomicAdd(&cursors[n], 1);
        bucket[p] = e;
    }
}

// one wave per node: rank by (t asc, id asc) via shuffles (cnt<=64)
__global__ void k_sortseg(const float* __restrict__ t, const int* __restrict__ offsets,
                          const int* __restrict__ bucket, int* __restrict__ sorted_id) {
    int wid = (blockIdx.x * 256 + threadIdx.x) >> 6;
    int ln = threadIdx.x & 63;
    int beg = offsets[wid], end = offsets[wid + 1];
    int cnt = end - beg;
    int e = 0; float tv = 0.f;
    if (ln < cnt) { e = bucket[beg + ln]; tv = t[e]; }
    int rank = 0;
    for (int j = 0; j < cnt; j++) {
        float tj = __shfl(tv, j);
        int ej = __shfl(e, j);
        rank += (tj < tv) || (tj == tv && ej < e);
    }
    if (ln < cnt) sorted_id[beg + rank] = e;
}

// ================= phase 2: serial recurrence =================
// 16 count-grouped nodes/block. W bf16 in regs (wave owns 64 outdims). h fp32 in
// regs. x=(m+h) via LDS bf16. sid lists staged ONCE into LDS (clamped repeats) so
// per-step addressing is a ds_read broadcast — the vmem queue never drains on an
// address dependency. msg prefetched depth-3 into registers; raw lgkm-only barrier.

__launch_bounds__(256, 2)
__global__ void k_gru(const float* __restrict__ msg, const float* __restrict__ W,
                      const float* __restrict__ b, const int* __restrict__ offsets,
                      const int* __restrict__ sorted_id, const int* __restrict__ perm,
                      float* __restrict__ out) {
    __shared__ __bf16 xA[2][16 * XA_STRIDE];  // 17.9 KB
    __shared__ int sidT[16][SMAX];            // 4 KB

    int tid  = threadIdx.x;
    int wave = tid >> 6;
    int lane = tid & 63;
    int q    = lane >> 4;
    int l    = lane & 15;
    int node0 = blockIdx.x * 16;

    // ---- W fragments (B operand: B[k][n]=W[n][k]; lane n=64w+16t4+l, k=32c+8q+j) ----
    bf16x8 wf[8][4];
#pragma unroll
    for (int t4 = 0; t4 < 4; t4++) {
        const float* wr = W + (64 * wave + 16 * t4 + l) * D_DIM;
#pragma unroll
        for (int c = 0; c < 8; c++) {
            int k0 = 32 * c + 8 * q;
            float4 w0 = *(const float4*)(wr + k0);
            float4 w1 = *(const float4*)(wr + k0 + 4);
            bf16x8 f;
            f[0] = (__bf16)w0.x; f[1] = (__bf16)w0.y; f[2] = (__bf16)w0.z; f[3] = (__bf16)w0.w;
            f[4] = (__bf16)w1.x; f[5] = (__bf16)w1.y; f[6] = (__bf16)w1.z; f[7] = (__bf16)w1.w;
            wf[c][t4] = f;
        }
    }
    float bias[4];
#pragma unroll
    for (int t4 = 0; t4 < 4; t4++) bias[t4] = b[64 * wave + 16 * t4 + l];

    // quad q owns C/D rows 4q+r
    int nodeC[4], cnt4[4];
#pragma unroll
    for (int r = 0; r < 4; r++) {
        int n = perm[node0 + 4 * q + r];
        nodeC[r] = n;
        cnt4[r] = offsets[n + 1] - offsets[n];
    }
    int nfirst = perm[node0];
    int S = min(offsets[nfirst + 1] - offsets[nfirst], SMAX);

    // ---- stage sid lists into LDS (entries >= cnt repeat the last valid sid) ----
    {
        int i = tid >> 4;                 // node row 0..15
        int ni = perm[node0 + i];
        int o0 = offsets[ni];
        int cn = offsets[ni + 1] - o0;
#pragma unroll
        for (int j = tid & 15; j < SMAX; j += 16)
            sidT[i][j] = (cn > 0) ? sorted_id[o0 + min(j, cn - 1)] : 0;
    }
    BAR();

    float h[4][4];
#pragma unroll
    for (int t4 = 0; t4 < 4; t4++)
#pragma unroll
        for (int r = 0; r < 4; r++) h[t4][r] = 0.f;

    // ---- prologue: x_0 = m_0 (sync); mvA = m_1, mvB = m_2 (in flight) ----
    float mvA[4][4], mvB[4][4], mvC[4][4];
#pragma unroll
    for (int r = 0; r < 4; r++) {
        const float* m0 = msg + (long)sidT[4 * q + r][0] * D_DIM;
#pragma unroll
        for (int t4 = 0; t4 < 4; t4++)
            xA[0][(4 * q + r) * XA_STRIDE + 64 * wave + 16 * t4 + l] =
                (__bf16)m0[64 * wave + 16 * t4 + l];
    }
#pragma unroll
    for (int r = 0; r < 4; r++) {
        const float* m1 = msg + (long)sidT[4 * q + r][1] * D_DIM;
#pragma unroll
        for (int t4 = 0; t4 < 4; t4++) mvA[r][t4] = m1[64 * wave + 16 * t4 + l];
    }
#pragma unroll
    for (int r = 0; r < 4; r++) {
        const float* m2 = msg + (long)sidT[4 * q + r][2] * D_DIM;
#pragma unroll
        for (int t4 = 0; t4 < 4; t4++) mvB[r][t4] = m2[64 * wave + 16 * t4 + l];
    }
    BAR();

    // step s: MFMA x_s; epilogue consumes cur=m_{s+1}, writes x_{s+1};
    // prefetches m_{s+3} into nxt (consumed 2 steps later -> full latency cover)
    auto step = [&](int s, float (&cur)[4][4], float (&nxt)[4][4]) {
        int slot = min(s + 3, SMAX - 1);
#pragma unroll
        for (int r = 0; r < 4; r++) {
            const float* mrow = msg + (long)sidT[4 * q + r][slot] * D_DIM;
#pragma unroll
            for (int t4 = 0; t4 < 4; t4++) nxt[r][t4] = mrow[64 * wave + 16 * t4 + l];
        }

        const __bf16* buf = xA[s & 1];
        f32x4 acc[4];
#pragma unroll
        for (int t4 = 0; t4 < 4; t4++) acc[t4] = (f32x4){0.f, 0.f, 0.f, 0.f};
#pragma unroll
        for (int c = 0; c < 8; c++) {
            bf16x8 a = *(const bf16x8*)(buf + l * XA_STRIDE + 32 * c + 8 * q);
#pragma unroll
            for (int t4 = 0; t4 < 4; t4++)
                acc[t4] = __builtin_amdgcn_mfma_f32_16x16x32_bf16(a, wf[c][t4], acc[t4], 0, 0, 0);
        }

        __bf16* nbuf = xA[(s + 1) & 1];
#pragma unroll
        for (int t4 = 0; t4 < 4; t4++) {
#pragma unroll
            for (int r = 0; r < 4; r++) {
                float hn = acc[t4][r] + bias[t4];
                bool valid = s < cnt4[r];
                h[t4][r] = valid ? hn : h[t4][r];
                nbuf[(4 * q + r) * XA_STRIDE + 64 * wave + 16 * t4 + l] =
                    (__bf16)(h[t4][r] + cur[r][t4]);
            }
        }
        BAR();
    };

    int s = 0;
    while (s < S) {
        step(s, mvA, mvC); s++;
        if (s >= S) break;
        step(s, mvB, mvA); s++;
        if (s >= S) break;
        step(s, mvC, mvB); s++;
    }

    // ---- write fp32 h (0 for empty nodes) ----
#pragma unroll
    for (int t4 = 0; t4 < 4; t4++)
#pragma unroll
        for (int r = 0; r < 4; r++)
            out[(long)nodeC[r] * D_DIM + 64 * wave + 16 * t4 + l] = h[t4][r];
}

// ================= launch =================

extern "C" void kernel_launch(void* const* d_in, const int* in_sizes, int n_in,
                              void* d_out, int out_size, void* d_ws, size_t ws_size,
                              hipStream_t stream) {
    const float* msg   = (const float*)d_in[0];
    const int*   index = (const int*)d_in[1];
    const float* t     = (const float*)d_in[2];
    const float* W     = (const float*)d_in[4];
    const float* b     = (const float*)d_in[5];
    float* out = (float*)d_out;

    int* ws = (int*)d_ws;
    int* counts    = ws;                // [8192]
    int* cursors   = ws + 8192;         // [8192]
    int* offsets   = ws + 16384;        // [8193]
    int* perm      = ws + 24584;        // [8192]
    int* bucket    = ws + 32776;        // [131072]
    int* sorted_id = ws + 163848;       // [131072]

    hipMemsetAsync(counts, 0, 16384 * sizeof(int), stream);  // counts + cursors

    k_count<<<E_MSGS / 256, 256, 0, stream>>>(index, counts);
    k_prep<<<1, 1024, 0, stream>>>(counts, offsets, perm);
    k_scatter<<<E_MSGS / 256, 256, 0, stream>>>(index, offsets, cursors, bucket);
    k_sortseg<<<N_NODES * 64 / 256, 256, 0, stream>>>(t, offsets, bucket, sorted_id);
    k_gru<<<N_NODES / 16, 256, 0, stream>>>(msg, W, b, offsets, sorted_id, perm, out);
}